// Round 9
// baseline (929.188 us; speedup 1.0000x reference)
//
#include <hip/hip_runtime.h>
#include <hip/hip_bf16.h>

#define N_NODES 50000
#define N_EDGES 800000
#define E2 (N_EDGES + N_NODES)   // with self loops = 850000
#define PSTR (E2 + 16)           // padded plane stride
#define F_IN 256
#define HID 64
#define HEADS 8
#define HO (HEADS * HID)         // 512
#define N_CLS 16
#define NEG_SLOPE 0.2f

typedef short short8 __attribute__((ext_vector_type(8)));
typedef float f32x4 __attribute__((ext_vector_type(4)));

__device__ __forceinline__ float bf2f(unsigned int hi16) { return __uint_as_float(hi16); }
__device__ __forceinline__ unsigned short f2bfu(float f) {
    return __bfloat16_as_ushort(__float2bfloat16(f));
}

// ---------------- convert x (fp32) -> xb (bf16) ----------------
__global__ __launch_bounds__(256) void convert_x_kernel(const float4* __restrict__ x,
                                                        uint4* __restrict__ xb) {
    int i = blockIdx.x * blockDim.x + threadIdx.x;
    if (i >= N_NODES * F_IN / 8) return;
    float4 v0 = x[i * 2], v1 = x[i * 2 + 1];
    uint4 o;
    o.x = (unsigned)f2bfu(v0.x) | ((unsigned)f2bfu(v0.y) << 16);
    o.y = (unsigned)f2bfu(v0.z) | ((unsigned)f2bfu(v0.w) << 16);
    o.z = (unsigned)f2bfu(v1.x) | ((unsigned)f2bfu(v1.y) << 16);
    o.w = (unsigned)f2bfu(v1.z) | ((unsigned)f2bfu(v1.w) << 16);
    xb[i] = o;
}

// ---------------- convert + transpose W1 -> wt[n][k] (bf16) ----------------
__global__ __launch_bounds__(256) void convert_wt_kernel(const float* __restrict__ W,
                                                         unsigned short* __restrict__ wt) {
    int i = blockIdx.x * blockDim.x + threadIdx.x;
    if (i >= F_IN * HO) return;
    int k = i / HO, n = i % HO;
    wt[n * F_IN + k] = f2bfu(W[i]);
}

// ---------------- pack W2 (512x16 fp32) -> fragment-ready bf16 ----------------
__global__ __launch_bounds__(256) void convert_w2_kernel(const float* __restrict__ W2,
                                                         unsigned short* __restrict__ w2p) {
    int idx = blockIdx.x * blockDim.x + threadIdx.x;
    if (idx >= HO * N_CLS) return;
    int j = idx & 7, l = (idx >> 3) & 63, c = idx >> 9;
    int k = c * 32 + ((l >> 4) & 3) * 8 + j;
    int col = l & 15;
    w2p[idx] = f2bfu(W2[k * N_CLS + col]);
}

// ---------------- GEMM1 (bf16 MFMA): h1 = x @ W1, fused attn scalars ----------------
// h1 stored SLICE-MAJOR: h1s[slice=f>>5][node][f&31]; one slice table = 3.2 MB (fits XCD L2)
#define LDK 40
__global__ __launch_bounds__(256) void gemm1_mfma_kernel(const unsigned short* __restrict__ xb,
                                                         const unsigned short* __restrict__ wt,
                                                         const float* __restrict__ as1,
                                                         const float* __restrict__ ad1,
                                                         unsigned short* __restrict__ h1s,
                                                         float* __restrict__ es1,
                                                         float* __restrict__ ed1) {
    __shared__ unsigned short sA[128 * LDK];
    __shared__ unsigned short sB[128 * LDK];
    int t = threadIdx.x;
    int m0 = blockIdx.y * 128, n0 = blockIdx.x * 128;
    int wid = t >> 6, lane = t & 63;
    int wr = wid >> 1, wc = wid & 1;
    int rl = lane & 15, kg = lane >> 4;
    f32x4 zero = {0.f, 0.f, 0.f, 0.f};
    f32x4 acc[4][4];
#pragma unroll
    for (int m = 0; m < 4; m++)
#pragma unroll
        for (int n = 0; n < 4; n++) acc[m][n] = zero;

    int srow = t >> 2, sslot = t & 3;
    for (int k0 = 0; k0 < F_IN; k0 += 32) {
#pragma unroll
        for (int p = 0; p < 2; p++) {
            int r = srow + p * 64;
            int gm = m0 + r;
            uint4 v = {0, 0, 0, 0};
            if (gm < N_NODES) v = *(const uint4*)(xb + (size_t)gm * F_IN + k0 + sslot * 8);
            *(uint4*)(sA + r * LDK + sslot * 8) = v;
        }
#pragma unroll
        for (int p = 0; p < 2; p++) {
            int r = srow + p * 64;
            uint4 v = *(const uint4*)(wt + (size_t)(n0 + r) * F_IN + k0 + sslot * 8);
            *(uint4*)(sB + r * LDK + sslot * 8) = v;
        }
        __syncthreads();
        short8 af[4], bfr[4];
#pragma unroll
        for (int m = 0; m < 4; m++)
            af[m] = *(const short8*)(sA + (wr * 64 + m * 16 + rl) * LDK + kg * 8);
#pragma unroll
        for (int n = 0; n < 4; n++)
            bfr[n] = *(const short8*)(sB + (wc * 64 + n * 16 + rl) * LDK + kg * 8);
#pragma unroll
        for (int m = 0; m < 4; m++)
#pragma unroll
            for (int n = 0; n < 4; n++)
                acc[m][n] = __builtin_amdgcn_mfma_f32_16x16x32_bf16(af[m], bfr[n], acc[m][n], 0, 0, 0);
        __syncthreads();
    }

    int h = (n0 + wc * 64) >> 6;
    float asv[4], adv[4];
#pragma unroll
    for (int n = 0; n < 4; n++) {
        asv[n] = as1[h * HID + n * 16 + rl];
        adv[n] = ad1[h * HID + n * 16 + rl];
    }
#pragma unroll
    for (int m = 0; m < 4; m++) {
#pragma unroll
        for (int reg = 0; reg < 4; reg++) {
            int gr = m0 + wr * 64 + m * 16 + kg * 4 + reg;
            float pa = 0.f, pd = 0.f;
#pragma unroll
            for (int n = 0; n < 4; n++) {
                float v = acc[m][n][reg];
                pa += v * asv[n];
                pd += v * adv[n];
            }
#pragma unroll
            for (int o = 8; o; o >>= 1) { pa += __shfl_xor(pa, o); pd += __shfl_xor(pd, o); }
            if (gr < N_NODES) {
#pragma unroll
                for (int n = 0; n < 4; n++) {
                    int gc = n0 + wc * 64 + n * 16 + rl;
                    int slice = gc >> 5;
                    h1s[(size_t)slice * N_NODES * 32 + (size_t)gr * 32 + (gc & 31)] =
                        f2bfu(acc[m][n][reg]);
                }
                if (rl == 0) {
                    es1[gr * HEADS + h] = pa;
                    ed1[gr * HEADS + h] = pd;
                }
            }
        }
    }
}

// --------------- degree histogram ---------------
__global__ __launch_bounds__(256) void hist_kernel(const int* __restrict__ ei, int* __restrict__ deg) {
    int e = blockIdx.x * blockDim.x + threadIdx.x;
    if (e >= E2) return;
    int dst = (e < N_EDGES) ? ei[N_EDGES + e] : (e - N_EDGES);
    atomicAdd(&deg[dst], 1);
}

// --------------- degree counting-sort: perm groups nodes of equal degree, rank = inverse ---------------
__global__ __launch_bounds__(256) void dhist_kernel(const int* __restrict__ deg, int* __restrict__ dhist) {
    int n = blockIdx.x * blockDim.x + threadIdx.x;
    if (n >= N_NODES) return;
    atomicAdd(&dhist[min(deg[n], 255)], 1);
}

__global__ __launch_bounds__(256) void dscan_kernel(const int* __restrict__ dhist, int* __restrict__ dbase) {
    int t = threadIdx.x;
    int v = dhist[t];
    __shared__ int s[256];
    s[t] = v; __syncthreads();
    for (int o = 1; o < 256; o <<= 1) {
        int tv = (t >= o) ? s[t - o] : 0;
        __syncthreads();
        s[t] += tv;
        __syncthreads();
    }
    dbase[t] = s[t] - v;   // exclusive
}

__global__ __launch_bounds__(256) void dperm_kernel(const int* __restrict__ deg,
                                                    const int* __restrict__ dbase,
                                                    int* __restrict__ dcur,
                                                    int* __restrict__ perm,
                                                    int* __restrict__ rank) {
    int n = blockIdx.x * blockDim.x + threadIdx.x;
    if (n >= N_NODES) return;
    int b = min(deg[n], 255);
    int pos = dbase[b] + atomicAdd(&dcur[b], 1);
    perm[pos] = n;
    rank[n] = pos;
}

// --------------- exclusive scan of PERMUTED degrees -> poff ---------------
#define NBLK_SCAN ((N_NODES + 255) / 256)   // 196
__global__ __launch_bounds__(256) void scan1_kernel(const int* __restrict__ deg,
                                                    const int* __restrict__ perm,
                                                    int* __restrict__ bsum) {
    int i = blockIdx.x * 256 + threadIdx.x;
    int v = (i < N_NODES) ? deg[perm[i]] : 0;
#pragma unroll
    for (int o = 32; o; o >>= 1) v += __shfl_xor(v, o);
    __shared__ int ws_[4];
    if ((threadIdx.x & 63) == 0) ws_[threadIdx.x >> 6] = v;
    __syncthreads();
    if (threadIdx.x == 0) bsum[blockIdx.x] = ws_[0] + ws_[1] + ws_[2] + ws_[3];
}

__global__ __launch_bounds__(256) void scan2_kernel(const int* __restrict__ bsum, int* __restrict__ bbase) {
    int t = threadIdx.x;
    int v = (t < NBLK_SCAN) ? bsum[t] : 0;
    __shared__ int s[256];
    s[t] = v; __syncthreads();
    for (int o = 1; o < 256; o <<= 1) {
        int tv = (t >= o) ? s[t - o] : 0;
        __syncthreads();
        s[t] += tv;
        __syncthreads();
    }
    if (t < NBLK_SCAN) bbase[t] = s[t] - v;   // exclusive
}

__global__ __launch_bounds__(256) void scan3_kernel(const int* __restrict__ deg,
                                                    const int* __restrict__ perm,
                                                    const int* __restrict__ bbase,
                                                    int* __restrict__ poff) {
    int t = threadIdx.x;
    int i = blockIdx.x * 256 + t;
    int v = (i < N_NODES) ? deg[perm[i]] : 0;
    int lane = t & 63, wid = t >> 6;
    int sc = v;
#pragma unroll
    for (int o = 1; o < 64; o <<= 1) {
        int tv = __shfl_up(sc, o);
        if (lane >= o) sc += tv;
    }
    __shared__ int wsum[4];
    if (lane == 63) wsum[wid] = sc;
    __syncthreads();
    int wbase = 0;
    for (int k = 0; k < 4; k++) if (k < wid) wbase += wsum[k];
    if (i < N_NODES) poff[i] = bbase[blockIdx.x] + wbase + sc - v;
}

// fill: scatter edges into PERMUTED CSR slots
__global__ __launch_bounds__(256) void fill_kernel(const int* __restrict__ ei,
                                                   const int* __restrict__ poff,
                                                   const int* __restrict__ rank,
                                                   int* __restrict__ cursor,
                                                   int* __restrict__ srcs,
                                                   int* __restrict__ dsts) {
    int e = blockIdx.x * blockDim.x + threadIdx.x;
    if (e >= E2) return;
    int src, dst;
    if (e < N_EDGES) { src = ei[e]; dst = ei[N_EDGES + e]; }
    else { src = dst = e - N_EDGES; }
    int pos = atomicAdd(&cursor[dst], 1);
    int slot = poff[rank[dst]] + pos;
    srcs[slot] = src;
    dsts[slot] = dst;
}

// --------------- per-(slot, head) softmax weights p = exp(leaky(es+ed)), head-major planes ---------------
__global__ __launch_bounds__(256) void pk_kernel(const int* __restrict__ srcs,
                                                 const int* __restrict__ dsts,
                                                 const float* __restrict__ es1,
                                                 const float* __restrict__ ed1,
                                                 unsigned short* __restrict__ pcsr) {
    int j = blockIdx.x * blockDim.x + threadIdx.x;
    if (j >= E2) return;
    int s = srcs[j], d = dsts[j];
    float4 ea0 = *(const float4*)(es1 + (size_t)s * 8);
    float4 ea1 = *(const float4*)(es1 + (size_t)s * 8 + 4);
    float4 eb0 = *(const float4*)(ed1 + (size_t)d * 8);
    float4 eb1 = *(const float4*)(ed1 + (size_t)d * 8 + 4);
    float e[8] = {ea0.x + eb0.x, ea0.y + eb0.y, ea0.z + eb0.z, ea0.w + eb0.w,
                  ea1.x + eb1.x, ea1.y + eb1.y, ea1.z + eb1.z, ea1.w + eb1.w};
#pragma unroll
    for (int h = 0; h < 8; h++) {
        float v = fmaxf(e[h], NEG_SLOPE * e[h]);
        pcsr[(size_t)h * PSTR + j] = f2bfu(__expf(v));
    }
}

// --------------- layer-1 aggregation: slice-affine, 8 equal-degree nodes/wave, streaming CSR ---------------
// grid: 2 phases x 1563 node-blocks x 8 slices; blockIdx%8==slice%8 -> XCD affinity.
// wave = 8 consecutive PERMUTED positions x 1 slice; lane = (sub=node 0..7, fl=feat-quad 0..7)
#define NGRP 6250            // node groups of 8 per slice (50000/8)
#define NBLK1 1563           // ceil(6250/4)
__global__ __launch_bounds__(256) void agg1_kernel(const unsigned short* __restrict__ h1s,
                                                   const unsigned short* __restrict__ pcsr,
                                                   const int* __restrict__ srcs,
                                                   const int* __restrict__ poff,
                                                   const int* __restrict__ deg,
                                                   const int* __restrict__ perm,
                                                   const float* __restrict__ b1,
                                                   unsigned short* __restrict__ out1b) {
    int b = blockIdx.x;
    int phase = b / (NBLK1 * 8);
    int r = b - phase * (NBLK1 * 8);
    int slice = phase * 8 + (r & 7);
    int wid = threadIdx.x >> 6, lane = threadIdx.x & 63;
    int ng = (r >> 3) * 4 + wid;
    if (ng >= NGRP) return;
    int sub = lane >> 3;     // node within group
    int fl = lane & 7;       // feature quad (4 feats, uint2)
    int g = ng * 8 + sub;    // permuted position
    int node = perm[g];
    int head = slice >> 1;
    int o = poff[g], d = deg[node];
    const unsigned short* tab = h1s + (size_t)slice * N_NODES * 32;
    const unsigned short* ph = pcsr + (size_t)head * PSTR;
    int dmax = d;
#pragma unroll
    for (int m = 8; m <= 32; m <<= 1) dmax = max(dmax, __shfl_xor(dmax, m));
    float den = 0.f, acc0 = 0.f, acc1 = 0.f, acc2 = 0.f, acc3 = 0.f;
    for (int i = 0; i < dmax; ++i) {
        bool valid = i < d;
        int slot = o + (valid ? i : 0);
        unsigned short pb = __builtin_nontemporal_load(ph + slot);
        int s = __builtin_nontemporal_load(srcs + slot);
        float p = bf2f((unsigned)pb << 16);
        p = valid ? p : 0.f;
        uint2 raw = *(const uint2*)(tab + (size_t)s * 32 + fl * 4);
        den += p;
        acc0 += p * bf2f(raw.x << 16);
        acc1 += p * bf2f(raw.x & 0xffff0000u);
        acc2 += p * bf2f(raw.y << 16);
        acc3 += p * bf2f(raw.y & 0xffff0000u);
    }
    float inv = 1.f / (den + 1e-16f);
    int fb = slice * 32 + fl * 4;
    float v0 = acc0 * inv + b1[fb + 0];
    float v1 = acc1 * inv + b1[fb + 1];
    float v2 = acc2 * inv + b1[fb + 2];
    float v3 = acc3 * inv + b1[fb + 3];
    v0 = (v0 > 0.f) ? v0 : (__expf(v0) - 1.f);
    v1 = (v1 > 0.f) ? v1 : (__expf(v1) - 1.f);
    v2 = (v2 > 0.f) ? v2 : (__expf(v2) - 1.f);
    v3 = (v3 > 0.f) ? v3 : (__expf(v3) - 1.f);
    unsigned lo = (unsigned)f2bfu(v0) | ((unsigned)f2bfu(v1) << 16);
    unsigned hi = (unsigned)f2bfu(v2) | ((unsigned)f2bfu(v3) << 16);
    unsigned long long pk64 = (unsigned long long)lo | ((unsigned long long)hi << 32);
    *(unsigned long long*)(out1b + (size_t)node * HO + fb) = pk64;
}

// --------------- layer-2 MFMA GEMM (512->16, bf16) + fused attention scalars ---------------
__global__ __launch_bounds__(256) void layer2_mfma_kernel(const unsigned short* __restrict__ act,
                                                          const unsigned short* __restrict__ w2p,
                                                          const float* __restrict__ as2,
                                                          const float* __restrict__ ad2,
                                                          unsigned short* __restrict__ h2b,
                                                          float* __restrict__ es2,
                                                          float* __restrict__ ed2) {
    int wave = (blockIdx.x * blockDim.x + threadIdx.x) >> 6;
    int lane = threadIdx.x & 63;
    int m0 = wave * 16;
    if (m0 >= N_NODES) return;
    int rl = lane & 15, kg = lane >> 4;
    int row = m0 + rl;
    f32x4 acc = {0.f, 0.f, 0.f, 0.f};
    const unsigned short* arow = act + (size_t)row * HO + kg * 8;
#pragma unroll
    for (int c = 0; c < 16; c++) {
        short8 af = *(const short8*)(arow + c * 32);
        short8 bf = *(const short8*)(w2p + (c * 64 + lane) * 8);
        acc = __builtin_amdgcn_mfma_f32_16x16x32_bf16(af, bf, acc, 0, 0, 0);
    }
    float a_s = as2[rl], a_d = ad2[rl];
#pragma unroll
    for (int reg = 0; reg < 4; reg++) {
        int r = m0 + kg * 4 + reg;
        float v = acc[reg];
        float pa = v * a_s, pd = v * a_d;
#pragma unroll
        for (int o = 8; o; o >>= 1) { pa += __shfl_xor(pa, o); pd += __shfl_xor(pd, o); }
        h2b[r * N_CLS + rl] = f2bfu(v);
        if (rl == 0) { es2[r] = pa; ed2[r] = pd; }
    }
}

// --------------- layer-2 fused score + softmax (no-max) + aggregation + log_softmax ---------------
// one wave per PERMUTED node position (streaming CSR slots)
__global__ __launch_bounds__(256) void agg2_kernel(const unsigned short* __restrict__ h2b,
                                                   const float* __restrict__ es2,
                                                   const float* __restrict__ ed2,
                                                   const int* __restrict__ srcs,
                                                   const int* __restrict__ poff,
                                                   const int* __restrict__ deg,
                                                   const int* __restrict__ perm,
                                                   const float* __restrict__ b2,
                                                   float* __restrict__ out) {
    int g = (blockIdx.x * blockDim.x + threadIdx.x) >> 6;
    int lane = threadIdx.x & 63;
    if (g >= N_NODES) return;
    int node = perm[g];
    int c = lane & 15, j = lane >> 4;
    int o = poff[g], d = deg[node];
    float edv = ed2[node];
    float den = 0.f, acc = 0.f;
    for (int i = j; i < d; i += 4) {
        int s = srcs[o + i];
        float e = es2[s] + edv;
        e = (e > 0.f) ? e : NEG_SLOPE * e;
        float p = __expf(e);
        den += p;
        acc += p * bf2f((unsigned)h2b[s * N_CLS + c] << 16);
    }
#pragma unroll
    for (int o2 = 16; o2 <= 32; o2 <<= 1) {
        den += __shfl_xor(den, o2);
        acc += __shfl_xor(acc, o2);
    }
    float v = acc / (den + 1e-16f) + b2[c];
    float mm = v;
#pragma unroll
    for (int o2 = 8; o2; o2 >>= 1) mm = fmaxf(mm, __shfl_xor(mm, o2));
    float se = __expf(v - mm);
#pragma unroll
    for (int o2 = 8; o2; o2 >>= 1) se += __shfl_xor(se, o2);
    if (lane < N_CLS) out[node * N_CLS + c] = v - mm - logf(se);
}

extern "C" void kernel_launch(void* const* d_in, const int* in_sizes, int n_in,
                              void* d_out, int out_size, void* d_ws, size_t ws_size,
                              hipStream_t stream) {
    const float* x   = (const float*)d_in[0];
    const int*   ei  = (const int*)d_in[1];
    const float* W1  = (const float*)d_in[2];
    const float* as1 = (const float*)d_in[3];
    const float* ad1 = (const float*)d_in[4];
    const float* b1  = (const float*)d_in[5];
    const float* W2  = (const float*)d_in[6];
    const float* as2 = (const float*)d_in[7];
    const float* ad2 = (const float*)d_in[8];
    const float* b2  = (const float*)d_in[9];
    float* out = (float*)d_out;

    // workspace carve
    unsigned short* usw = (unsigned short*)d_ws;
    unsigned short* h1s   = usw;                                  // 25.6M (slice-major)
    unsigned short* xb    = h1s + (size_t)N_NODES * HO;           // 12.8M
    unsigned short* wt    = xb + (size_t)N_NODES * F_IN;          // 131k
    unsigned short* w2p   = wt + F_IN * HO;                       // 8192
    unsigned short* out1b = w2p + HO * N_CLS;                     // 25.6M
    unsigned short* h2b   = out1b + (size_t)N_NODES * HO;         // 800k
    unsigned short* pcsr  = h2b + (size_t)N_NODES * N_CLS;        // 8*PSTR
    float* fw = (float*)(pcsr + (size_t)HEADS * PSTR);
    float* es1  = fw;                                             // 400k
    float* ed1  = es1 + (size_t)N_NODES * HEADS;                  // 400k
    float* es2  = ed1 + (size_t)N_NODES * HEADS;                  // 50k
    float* ed2  = es2 + N_NODES;                                  // 50k
    int* deg    = (int*)(ed2 + N_NODES);                          // 50k  <- memset
    int* cursor = deg + N_NODES;                                  // 50k  <- memset
    int* dhist  = cursor + N_NODES;                               // 256  <- memset
    int* dcur   = dhist + 256;                                    // 256  <- memset
    int* dbase  = dcur + 256;                                     // 256
    int* poff   = dbase + 256;                                    // 50k
    int* perm   = poff + N_NODES;                                 // 50k
    int* rank   = perm + N_NODES;                                 // 50k
    int* srcs   = rank + N_NODES;                                 // PSTR
    int* dsts   = srcs + PSTR;                                    // E2
    int* bsum   = dsts + E2;                                      // 256
    int* bbase  = bsum + 256;                                     // 256

    hipMemsetAsync(deg, 0, (2 * N_NODES + 512) * sizeof(int), stream);  // deg,cursor,dhist,dcur

    // converts
    convert_x_kernel<<<(N_NODES * F_IN / 8 + 255) / 256, 256, 0, stream>>>((const float4*)x, (uint4*)xb);
    convert_wt_kernel<<<(F_IN * HO + 255) / 256, 256, 0, stream>>>(W1, wt);
    convert_w2_kernel<<<(HO * N_CLS + 255) / 256, 256, 0, stream>>>(W2, w2p);

    // layer 1 GEMM (bf16 MFMA, fused attention scalars, slice-major h1)
    gemm1_mfma_kernel<<<dim3(HO / 128, (N_NODES + 127) / 128), 256, 0, stream>>>(
        xb, wt, as1, ad1, h1s, es1, ed1);

    // degree histogram + degree counting-sort
    hist_kernel<<<(E2 + 255) / 256, 256, 0, stream>>>(ei, deg);
    dhist_kernel<<<(N_NODES + 255) / 256, 256, 0, stream>>>(deg, dhist);
    dscan_kernel<<<1, 256, 0, stream>>>(dhist, dbase);
    dperm_kernel<<<(N_NODES + 255) / 256, 256, 0, stream>>>(deg, dbase, dcur, perm, rank);

    // exclusive scan of permuted degrees -> poff; fill permuted CSR
    scan1_kernel<<<NBLK_SCAN, 256, 0, stream>>>(deg, perm, bsum);
    scan2_kernel<<<1, 256, 0, stream>>>(bsum, bbase);
    scan3_kernel<<<NBLK_SCAN, 256, 0, stream>>>(deg, perm, bbase, poff);
    fill_kernel<<<(E2 + 255) / 256, 256, 0, stream>>>(ei, poff, rank, cursor, srcs, dsts);

    // per-(slot, head) softmax weights
    pk_kernel<<<(E2 + 255) / 256, 256, 0, stream>>>(srcs, dsts, es1, ed1, pcsr);

    // layer-1 aggregation: slice-affine, 8 equal-degree nodes per wave, streaming CSR
    agg1_kernel<<<2 * NBLK1 * 8, 256, 0, stream>>>(h1s, pcsr, srcs, poff, deg, perm, b1, out1b);

    // layer-2 MFMA GEMM + attention scalars
    layer2_mfma_kernel<<<((N_NODES / 16) * 64 + 255) / 256, 256, 0, stream>>>(
        out1b, w2p, as2, ad2, h2b, es2, ed2);

    // layer-2 fused score+softmax+aggregation + log_softmax
    agg2_kernel<<<(N_NODES + 3) / 4, 256, 0, stream>>>(h2b, es2, ed2, srcs, poff, deg, perm, b2, out);
}

// Round 10
// 666.932 us; speedup vs baseline: 1.3932x; 1.3932x over previous
//
#include <hip/hip_runtime.h>
#include <hip/hip_bf16.h>

#define N_NODES 50000
#define N_EDGES 800000
#define E2 (N_EDGES + N_NODES)   // with self loops = 850000
#define PSTR (E2 + 16)           // padded plane stride
#define F_IN 256
#define HID 64
#define HEADS 8
#define HO (HEADS * HID)         // 512
#define N_CLS 16
#define NEG_SLOPE 0.2f

typedef short short8 __attribute__((ext_vector_type(8)));
typedef float f32x4 __attribute__((ext_vector_type(4)));

__device__ __forceinline__ float bf2f(unsigned int hi16) { return __uint_as_float(hi16); }
__device__ __forceinline__ unsigned short f2bfu(float f) {
    return __bfloat16_as_ushort(__float2bfloat16(f));
}

// ---------------- convert x (fp32) -> xb (bf16) ----------------
__global__ __launch_bounds__(256) void convert_x_kernel(const float4* __restrict__ x,
                                                        uint4* __restrict__ xb) {
    int i = blockIdx.x * blockDim.x + threadIdx.x;
    if (i >= N_NODES * F_IN / 8) return;
    float4 v0 = x[i * 2], v1 = x[i * 2 + 1];
    uint4 o;
    o.x = (unsigned)f2bfu(v0.x) | ((unsigned)f2bfu(v0.y) << 16);
    o.y = (unsigned)f2bfu(v0.z) | ((unsigned)f2bfu(v0.w) << 16);
    o.z = (unsigned)f2bfu(v1.x) | ((unsigned)f2bfu(v1.y) << 16);
    o.w = (unsigned)f2bfu(v1.z) | ((unsigned)f2bfu(v1.w) << 16);
    xb[i] = o;
}

// ---------------- convert + transpose W1 -> wt[n][k] (bf16) ----------------
__global__ __launch_bounds__(256) void convert_wt_kernel(const float* __restrict__ W,
                                                         unsigned short* __restrict__ wt) {
    int i = blockIdx.x * blockDim.x + threadIdx.x;
    if (i >= F_IN * HO) return;
    int k = i / HO, n = i % HO;
    wt[n * F_IN + k] = f2bfu(W[i]);
}

// ---------------- pack W2 (512x16 fp32) -> fragment-ready bf16 ----------------
__global__ __launch_bounds__(256) void convert_w2_kernel(const float* __restrict__ W2,
                                                         unsigned short* __restrict__ w2p) {
    int idx = blockIdx.x * blockDim.x + threadIdx.x;
    if (idx >= HO * N_CLS) return;
    int j = idx & 7, l = (idx >> 3) & 63, c = idx >> 9;
    int k = c * 32 + ((l >> 4) & 3) * 8 + j;
    int col = l & 15;
    w2p[idx] = f2bfu(W2[k * N_CLS + col]);
}

// ---------------- GEMM1 (bf16 MFMA): h1 = x @ W1, fused attn scalars ----------------
// h1 stored SLICE-MAJOR: h1s[slice=f>>5][node][f&31]; one slice table = 3.2 MB (fits XCD L2)
#define LDK 40
__global__ __launch_bounds__(256) void gemm1_mfma_kernel(const unsigned short* __restrict__ xb,
                                                         const unsigned short* __restrict__ wt,
                                                         const float* __restrict__ as1,
                                                         const float* __restrict__ ad1,
                                                         unsigned short* __restrict__ h1s,
                                                         float* __restrict__ es1,
                                                         float* __restrict__ ed1) {
    __shared__ unsigned short sA[128 * LDK];
    __shared__ unsigned short sB[128 * LDK];
    int t = threadIdx.x;
    int m0 = blockIdx.y * 128, n0 = blockIdx.x * 128;
    int wid = t >> 6, lane = t & 63;
    int wr = wid >> 1, wc = wid & 1;
    int rl = lane & 15, kg = lane >> 4;
    f32x4 zero = {0.f, 0.f, 0.f, 0.f};
    f32x4 acc[4][4];
#pragma unroll
    for (int m = 0; m < 4; m++)
#pragma unroll
        for (int n = 0; n < 4; n++) acc[m][n] = zero;

    int srow = t >> 2, sslot = t & 3;
    for (int k0 = 0; k0 < F_IN; k0 += 32) {
#pragma unroll
        for (int p = 0; p < 2; p++) {
            int r = srow + p * 64;
            int gm = m0 + r;
            uint4 v = {0, 0, 0, 0};
            if (gm < N_NODES) v = *(const uint4*)(xb + (size_t)gm * F_IN + k0 + sslot * 8);
            *(uint4*)(sA + r * LDK + sslot * 8) = v;
        }
#pragma unroll
        for (int p = 0; p < 2; p++) {
            int r = srow + p * 64;
            uint4 v = *(const uint4*)(wt + (size_t)(n0 + r) * F_IN + k0 + sslot * 8);
            *(uint4*)(sB + r * LDK + sslot * 8) = v;
        }
        __syncthreads();
        short8 af[4], bfr[4];
#pragma unroll
        for (int m = 0; m < 4; m++)
            af[m] = *(const short8*)(sA + (wr * 64 + m * 16 + rl) * LDK + kg * 8);
#pragma unroll
        for (int n = 0; n < 4; n++)
            bfr[n] = *(const short8*)(sB + (wc * 64 + n * 16 + rl) * LDK + kg * 8);
#pragma unroll
        for (int m = 0; m < 4; m++)
#pragma unroll
            for (int n = 0; n < 4; n++)
                acc[m][n] = __builtin_amdgcn_mfma_f32_16x16x32_bf16(af[m], bfr[n], acc[m][n], 0, 0, 0);
        __syncthreads();
    }

    int h = (n0 + wc * 64) >> 6;
    float asv[4], adv[4];
#pragma unroll
    for (int n = 0; n < 4; n++) {
        asv[n] = as1[h * HID + n * 16 + rl];
        adv[n] = ad1[h * HID + n * 16 + rl];
    }
#pragma unroll
    for (int m = 0; m < 4; m++) {
#pragma unroll
        for (int reg = 0; reg < 4; reg++) {
            int gr = m0 + wr * 64 + m * 16 + kg * 4 + reg;
            float pa = 0.f, pd = 0.f;
#pragma unroll
            for (int n = 0; n < 4; n++) {
                float v = acc[m][n][reg];
                pa += v * asv[n];
                pd += v * adv[n];
            }
#pragma unroll
            for (int o = 8; o; o >>= 1) { pa += __shfl_xor(pa, o); pd += __shfl_xor(pd, o); }
            if (gr < N_NODES) {
#pragma unroll
                for (int n = 0; n < 4; n++) {
                    int gc = n0 + wc * 64 + n * 16 + rl;
                    int slice = gc >> 5;
                    h1s[(size_t)slice * N_NODES * 32 + (size_t)gr * 32 + (gc & 31)] =
                        f2bfu(acc[m][n][reg]);
                }
                if (rl == 0) {
                    es1[gr * HEADS + h] = pa;
                    ed1[gr * HEADS + h] = pd;
                }
            }
        }
    }
}

// --------------- CSR build (natural node order) ---------------
__global__ __launch_bounds__(256) void hist_kernel(const int* __restrict__ ei, int* __restrict__ deg) {
    int e = blockIdx.x * blockDim.x + threadIdx.x;
    if (e >= E2) return;
    int dst = (e < N_EDGES) ? ei[N_EDGES + e] : (e - N_EDGES);
    atomicAdd(&deg[dst], 1);
}

#define NBLK_SCAN ((N_NODES + 255) / 256)   // 196
__global__ __launch_bounds__(256) void scan1_kernel(const int* __restrict__ deg, int* __restrict__ bsum) {
    int i = blockIdx.x * 256 + threadIdx.x;
    int v = (i < N_NODES) ? deg[i] : 0;
#pragma unroll
    for (int o = 32; o; o >>= 1) v += __shfl_xor(v, o);
    __shared__ int ws_[4];
    if ((threadIdx.x & 63) == 0) ws_[threadIdx.x >> 6] = v;
    __syncthreads();
    if (threadIdx.x == 0) bsum[blockIdx.x] = ws_[0] + ws_[1] + ws_[2] + ws_[3];
}

__global__ __launch_bounds__(256) void scan2_kernel(const int* __restrict__ bsum, int* __restrict__ bbase) {
    int t = threadIdx.x;
    int v = (t < NBLK_SCAN) ? bsum[t] : 0;
    __shared__ int s[256];
    s[t] = v; __syncthreads();
    for (int o = 1; o < 256; o <<= 1) {
        int tv = (t >= o) ? s[t - o] : 0;
        __syncthreads();
        s[t] += tv;
        __syncthreads();
    }
    if (t < NBLK_SCAN) bbase[t] = s[t] - v;   // exclusive
}

__global__ __launch_bounds__(256) void scan3_kernel(const int* __restrict__ deg,
                                                    const int* __restrict__ bbase,
                                                    int* __restrict__ off) {
    int t = threadIdx.x;
    int i = blockIdx.x * 256 + t;
    int v = (i < N_NODES) ? deg[i] : 0;
    int lane = t & 63, wid = t >> 6;
    int sc = v;
#pragma unroll
    for (int o = 1; o < 64; o <<= 1) {
        int tv = __shfl_up(sc, o);
        if (lane >= o) sc += tv;
    }
    __shared__ int wsum[4];
    if (lane == 63) wsum[wid] = sc;
    __syncthreads();
    int wbase = 0;
    for (int k = 0; k < 4; k++) if (k < wid) wbase += wsum[k];
    if (i < N_NODES) off[i] = bbase[blockIdx.x] + wbase + sc - v;
}

__global__ __launch_bounds__(256) void fill_kernel(const int* __restrict__ ei,
                                                   const int* __restrict__ off,
                                                   int* __restrict__ cursor,
                                                   int* __restrict__ srcs,
                                                   int* __restrict__ dsts) {
    int e = blockIdx.x * blockDim.x + threadIdx.x;
    if (e >= E2) return;
    int src, dst;
    if (e < N_EDGES) { src = ei[e]; dst = ei[N_EDGES + e]; }
    else { src = dst = e - N_EDGES; }
    int pos = atomicAdd(&cursor[dst], 1);
    int slot = off[dst] + pos;
    srcs[slot] = src;
    dsts[slot] = dst;
}

// --------------- per-(slot, head) softmax weights p = exp(leaky(es+ed)), head-major planes ---------------
__global__ __launch_bounds__(256) void pk_kernel(const int* __restrict__ srcs,
                                                 const int* __restrict__ dsts,
                                                 const float* __restrict__ es1,
                                                 const float* __restrict__ ed1,
                                                 unsigned short* __restrict__ pcsr) {
    int j = blockIdx.x * blockDim.x + threadIdx.x;
    if (j >= E2) return;
    int s = srcs[j], d = dsts[j];
    float4 ea0 = *(const float4*)(es1 + (size_t)s * 8);
    float4 ea1 = *(const float4*)(es1 + (size_t)s * 8 + 4);
    float4 eb0 = *(const float4*)(ed1 + (size_t)d * 8);
    float4 eb1 = *(const float4*)(ed1 + (size_t)d * 8 + 4);
    float e[8] = {ea0.x + eb0.x, ea0.y + eb0.y, ea0.z + eb0.z, ea0.w + eb0.w,
                  ea1.x + eb1.x, ea1.y + eb1.y, ea1.z + eb1.z, ea1.w + eb1.w};
#pragma unroll
    for (int h = 0; h < 8; h++) {
        float v = fmaxf(e[h], NEG_SLOPE * e[h]);
        pcsr[(size_t)h * PSTR + j] = f2bfu(__expf(v));
    }
}

// --------------- layer-1 aggregation: slice-affine, 8 nodes/wave (natural order), NT everywhere ---------------
// grid: 2 phases x 1563 node-blocks x 8 slices; blockIdx%8==slice%8 -> XCD affinity.
// wave = 8 consecutive nodes x 1 slice; lane = (sub=node 0..7, fl=feat-quad 0..7). No cross-lane reduce.
#define NGRP 6250            // node groups of 8 (50000/8)
#define NBLK1 1563           // ceil(6250/4)
__global__ __launch_bounds__(256) void agg1_kernel(const unsigned short* __restrict__ h1s,
                                                   const unsigned short* __restrict__ pcsr,
                                                   const int* __restrict__ srcs,
                                                   const int* __restrict__ off,
                                                   const int* __restrict__ deg,
                                                   const float* __restrict__ b1,
                                                   unsigned short* __restrict__ out1b) {
    int b = blockIdx.x;
    int phase = b / (NBLK1 * 8);
    int r = b - phase * (NBLK1 * 8);
    int slice = phase * 8 + (r & 7);
    int wid = threadIdx.x >> 6, lane = threadIdx.x & 63;
    int ng = (r >> 3) * 4 + wid;
    if (ng >= NGRP) return;
    int sub = lane >> 3;     // node within group
    int fl = lane & 7;       // feature quad (4 feats, uint2)
    int node = ng * 8 + sub;
    int head = slice >> 1;
    int o = off[node], d = deg[node];
    const unsigned short* tab = h1s + (size_t)slice * N_NODES * 32;
    const unsigned short* ph = pcsr + (size_t)head * PSTR;
    int dmax = d;
#pragma unroll
    for (int m = 8; m <= 32; m <<= 1) dmax = max(dmax, __shfl_xor(dmax, m));
    float den = 0.f, acc0 = 0.f, acc1 = 0.f, acc2 = 0.f, acc3 = 0.f;
    for (int i = 0; i < dmax; ++i) {
        bool valid = i < d;
        int slot = o + (valid ? i : 0);
        unsigned short pb = __builtin_nontemporal_load(ph + slot);
        int s = __builtin_nontemporal_load(srcs + slot);
        float p = bf2f((unsigned)pb << 16);
        p = valid ? p : 0.f;
        uint2 raw = *(const uint2*)(tab + (size_t)s * 32 + fl * 4);
        den += p;
        acc0 += p * bf2f(raw.x << 16);
        acc1 += p * bf2f(raw.x & 0xffff0000u);
        acc2 += p * bf2f(raw.y << 16);
        acc3 += p * bf2f(raw.y & 0xffff0000u);
    }
    float inv = 1.f / (den + 1e-16f);
    int fb = slice * 32 + fl * 4;
    float v0 = acc0 * inv + b1[fb + 0];
    float v1 = acc1 * inv + b1[fb + 1];
    float v2 = acc2 * inv + b1[fb + 2];
    float v3 = acc3 * inv + b1[fb + 3];
    v0 = (v0 > 0.f) ? v0 : (__expf(v0) - 1.f);
    v1 = (v1 > 0.f) ? v1 : (__expf(v1) - 1.f);
    v2 = (v2 > 0.f) ? v2 : (__expf(v2) - 1.f);
    v3 = (v3 > 0.f) ? v3 : (__expf(v3) - 1.f);
    unsigned lo = (unsigned)f2bfu(v0) | ((unsigned)f2bfu(v1) << 16);
    unsigned hi = (unsigned)f2bfu(v2) | ((unsigned)f2bfu(v3) << 16);
    unsigned long long pk64 = (unsigned long long)lo | ((unsigned long long)hi << 32);
    __builtin_nontemporal_store(pk64, (unsigned long long*)(out1b + (size_t)node * HO + fb));
}

// --------------- layer-2 MFMA GEMM (512->16, bf16) + fused attention scalars ---------------
__global__ __launch_bounds__(256) void layer2_mfma_kernel(const unsigned short* __restrict__ act,
                                                          const unsigned short* __restrict__ w2p,
                                                          const float* __restrict__ as2,
                                                          const float* __restrict__ ad2,
                                                          unsigned short* __restrict__ h2b,
                                                          float* __restrict__ es2,
                                                          float* __restrict__ ed2) {
    int wave = (blockIdx.x * blockDim.x + threadIdx.x) >> 6;
    int lane = threadIdx.x & 63;
    int m0 = wave * 16;
    if (m0 >= N_NODES) return;
    int rl = lane & 15, kg = lane >> 4;
    int row = m0 + rl;
    f32x4 acc = {0.f, 0.f, 0.f, 0.f};
    const unsigned short* arow = act + (size_t)row * HO + kg * 8;
#pragma unroll
    for (int c = 0; c < 16; c++) {
        short8 af = *(const short8*)(arow + c * 32);
        short8 bf = *(const short8*)(w2p + (c * 64 + lane) * 8);
        acc = __builtin_amdgcn_mfma_f32_16x16x32_bf16(af, bf, acc, 0, 0, 0);
    }
    float a_s = as2[rl], a_d = ad2[rl];
#pragma unroll
    for (int reg = 0; reg < 4; reg++) {
        int r = m0 + kg * 4 + reg;
        float v = acc[reg];
        float pa = v * a_s, pd = v * a_d;
#pragma unroll
        for (int o = 8; o; o >>= 1) { pa += __shfl_xor(pa, o); pd += __shfl_xor(pd, o); }
        h2b[r * N_CLS + rl] = f2bfu(v);
        if (rl == 0) { es2[r] = pa; ed2[r] = pd; }
    }
}

// --------------- layer-2 fused score + softmax (no-max) + aggregation + log_softmax ---------------
__global__ __launch_bounds__(256) void agg2_kernel(const unsigned short* __restrict__ h2b,
                                                   const float* __restrict__ es2,
                                                   const float* __restrict__ ed2,
                                                   const int* __restrict__ srcs,
                                                   const int* __restrict__ off,
                                                   const int* __restrict__ deg,
                                                   const float* __restrict__ b2,
                                                   float* __restrict__ out) {
    int w = (blockIdx.x * blockDim.x + threadIdx.x) >> 6;
    int lane = threadIdx.x & 63;
    if (w >= N_NODES) return;
    int c = lane & 15, j = lane >> 4;
    int o = off[w], d = deg[w];
    float edv = ed2[w];
    float den = 0.f, acc = 0.f;
    for (int i = j; i < d; i += 4) {
        int s = srcs[o + i];
        float e = es2[s] + edv;
        e = (e > 0.f) ? e : NEG_SLOPE * e;
        float p = __expf(e);
        den += p;
        acc += p * bf2f((unsigned)h2b[s * N_CLS + c] << 16);
    }
#pragma unroll
    for (int o2 = 16; o2 <= 32; o2 <<= 1) {
        den += __shfl_xor(den, o2);
        acc += __shfl_xor(acc, o2);
    }
    float v = acc / (den + 1e-16f) + b2[c];
    float mm = v;
#pragma unroll
    for (int o2 = 8; o2; o2 >>= 1) mm = fmaxf(mm, __shfl_xor(mm, o2));
    float se = __expf(v - mm);
#pragma unroll
    for (int o2 = 8; o2; o2 >>= 1) se += __shfl_xor(se, o2);
    if (lane < N_CLS) out[w * N_CLS + c] = v - mm - logf(se);
}

extern "C" void kernel_launch(void* const* d_in, const int* in_sizes, int n_in,
                              void* d_out, int out_size, void* d_ws, size_t ws_size,
                              hipStream_t stream) {
    const float* x   = (const float*)d_in[0];
    const int*   ei  = (const int*)d_in[1];
    const float* W1  = (const float*)d_in[2];
    const float* as1 = (const float*)d_in[3];
    const float* ad1 = (const float*)d_in[4];
    const float* b1  = (const float*)d_in[5];
    const float* W2  = (const float*)d_in[6];
    const float* as2 = (const float*)d_in[7];
    const float* ad2 = (const float*)d_in[8];
    const float* b2  = (const float*)d_in[9];
    float* out = (float*)d_out;

    // workspace carve
    unsigned short* usw = (unsigned short*)d_ws;
    unsigned short* h1s   = usw;                                  // 25.6M (slice-major)
    unsigned short* xb    = h1s + (size_t)N_NODES * HO;           // 12.8M
    unsigned short* wt    = xb + (size_t)N_NODES * F_IN;          // 131k
    unsigned short* w2p   = wt + F_IN * HO;                       // 8192
    unsigned short* out1b = w2p + HO * N_CLS;                     // 25.6M
    unsigned short* h2b   = out1b + (size_t)N_NODES * HO;         // 800k
    unsigned short* pcsr  = h2b + (size_t)N_NODES * N_CLS;        // 8*PSTR
    float* fw = (float*)(pcsr + (size_t)HEADS * PSTR);
    float* es1  = fw;                                             // 400k
    float* ed1  = es1 + (size_t)N_NODES * HEADS;                  // 400k
    float* es2  = ed1 + (size_t)N_NODES * HEADS;                  // 50k
    float* ed2  = es2 + N_NODES;                                  // 50k
    int* deg    = (int*)(ed2 + N_NODES);                          // 50k  <- memset
    int* cursor = deg + N_NODES;                                  // 50k  <- memset
    int* off    = cursor + N_NODES;                               // 50k
    int* srcs   = off + N_NODES;                                  // PSTR
    int* dsts   = srcs + PSTR;                                    // E2
    int* bsum   = dsts + E2;                                      // 256
    int* bbase  = bsum + 256;                                     // 256

    hipMemsetAsync(deg, 0, 2 * N_NODES * sizeof(int), stream);  // deg + cursor

    // converts
    convert_x_kernel<<<(N_NODES * F_IN / 8 + 255) / 256, 256, 0, stream>>>((const float4*)x, (uint4*)xb);
    convert_wt_kernel<<<(F_IN * HO + 255) / 256, 256, 0, stream>>>(W1, wt);
    convert_w2_kernel<<<(HO * N_CLS + 255) / 256, 256, 0, stream>>>(W2, w2p);

    // layer 1 GEMM (bf16 MFMA, fused attention scalars, slice-major h1)
    gemm1_mfma_kernel<<<dim3(HO / 128, (N_NODES + 127) / 128), 256, 0, stream>>>(
        xb, wt, as1, ad1, h1s, es1, ed1);

    // CSR build (natural order)
    hist_kernel<<<(E2 + 255) / 256, 256, 0, stream>>>(ei, deg);
    scan1_kernel<<<NBLK_SCAN, 256, 0, stream>>>(deg, bsum);
    scan2_kernel<<<1, 256, 0, stream>>>(bsum, bbase);
    scan3_kernel<<<NBLK_SCAN, 256, 0, stream>>>(deg, bbase, off);
    fill_kernel<<<(E2 + 255) / 256, 256, 0, stream>>>(ei, off, cursor, srcs, dsts);

    // per-(slot, head) softmax weights
    pk_kernel<<<(E2 + 255) / 256, 256, 0, stream>>>(srcs, dsts, es1, ed1, pcsr);

    // layer-1 aggregation: slice-affine, 8 nodes per wave, NT loads + NT store
    agg1_kernel<<<2 * NBLK1 * 8, 256, 0, stream>>>(h1s, pcsr, srcs, off, deg, b1, out1b);

    // layer-2 MFMA GEMM + attention scalars
    layer2_mfma_kernel<<<((N_NODES / 16) * 64 + 255) / 256, 256, 0, stream>>>(
        out1b, w2p, as2, ad2, h2b, es2, ed2);

    // layer-2 fused score+softmax+aggregation + log_softmax
    agg2_kernel<<<(N_NODES + 3) / 4, 256, 0, stream>>>(h2b, es2, ed2, srcs, off, deg, b2, out);
}

// Round 11
// 487.728 us; speedup vs baseline: 1.9051x; 1.3674x over previous
//
#include <hip/hip_runtime.h>
#include <hip/hip_bf16.h>

#define N_NODES 50000
#define N_EDGES 800000
#define E2 (N_EDGES + N_NODES)   // with self loops = 850000
#define F_IN 256
#define HID 64
#define HEADS 8
#define HO (HEADS * HID)         // 512
#define N_CLS 16
#define NEG_SLOPE 0.2f

typedef short short8 __attribute__((ext_vector_type(8)));
typedef float f32x4 __attribute__((ext_vector_type(4)));

__device__ __forceinline__ float bf2f(unsigned int hi16) { return __uint_as_float(hi16); }
__device__ __forceinline__ unsigned short f2bfu(float f) {
    return __bfloat16_as_ushort(__float2bfloat16(f));
}
__device__ __forceinline__ unsigned packbf(float a, float b) {
    return (unsigned)f2bfu(a) | ((unsigned)f2bfu(b) << 16);
}

// ---------------- convert + transpose W1 -> wt[n][k] (bf16) ----------------
__global__ __launch_bounds__(256) void convert_wt_kernel(const float* __restrict__ W,
                                                         unsigned short* __restrict__ wt) {
    int i = blockIdx.x * blockDim.x + threadIdx.x;
    if (i >= F_IN * HO) return;
    int k = i / HO, n = i % HO;
    wt[n * F_IN + k] = f2bfu(W[i]);
}

// ---------------- GEMM1 (bf16 MFMA): h1 = x @ W1, fused attn scalars ----------------
// A staged directly from fp32 x (in-register convert). h1 row-major bf16.
#define LDK 40
__global__ __launch_bounds__(256) void gemm1_mfma_kernel(const float* __restrict__ x,
                                                         const unsigned short* __restrict__ wt,
                                                         const float* __restrict__ as1,
                                                         const float* __restrict__ ad1,
                                                         unsigned short* __restrict__ h1b,
                                                         float* __restrict__ es1,
                                                         float* __restrict__ ed1) {
    __shared__ unsigned short sA[128 * LDK];
    __shared__ unsigned short sB[128 * LDK];
    int t = threadIdx.x;
    int m0 = blockIdx.y * 128, n0 = blockIdx.x * 128;
    int wid = t >> 6, lane = t & 63;
    int wr = wid >> 1, wc = wid & 1;
    int rl = lane & 15, kg = lane >> 4;
    f32x4 zero = {0.f, 0.f, 0.f, 0.f};
    f32x4 acc[4][4];
#pragma unroll
    for (int m = 0; m < 4; m++)
#pragma unroll
        for (int n = 0; n < 4; n++) acc[m][n] = zero;

    int srow = t >> 2, sslot = t & 3;
    for (int k0 = 0; k0 < F_IN; k0 += 32) {
#pragma unroll
        for (int p = 0; p < 2; p++) {
            int r = srow + p * 64;
            int gm = m0 + r;
            uint4 v = {0, 0, 0, 0};
            if (gm < N_NODES) {
                const float* xg = x + (size_t)gm * F_IN + k0 + sslot * 8;
                float4 a0 = *(const float4*)xg;
                float4 a1 = *(const float4*)(xg + 4);
                v.x = packbf(a0.x, a0.y);
                v.y = packbf(a0.z, a0.w);
                v.z = packbf(a1.x, a1.y);
                v.w = packbf(a1.z, a1.w);
            }
            *(uint4*)(sA + r * LDK + sslot * 8) = v;
        }
#pragma unroll
        for (int p = 0; p < 2; p++) {
            int r = srow + p * 64;
            uint4 v = *(const uint4*)(wt + (size_t)(n0 + r) * F_IN + k0 + sslot * 8);
            *(uint4*)(sB + r * LDK + sslot * 8) = v;
        }
        __syncthreads();
        short8 af[4], bfr[4];
#pragma unroll
        for (int m = 0; m < 4; m++)
            af[m] = *(const short8*)(sA + (wr * 64 + m * 16 + rl) * LDK + kg * 8);
#pragma unroll
        for (int n = 0; n < 4; n++)
            bfr[n] = *(const short8*)(sB + (wc * 64 + n * 16 + rl) * LDK + kg * 8);
#pragma unroll
        for (int m = 0; m < 4; m++)
#pragma unroll
            for (int n = 0; n < 4; n++)
                acc[m][n] = __builtin_amdgcn_mfma_f32_16x16x32_bf16(af[m], bfr[n], acc[m][n], 0, 0, 0);
        __syncthreads();
    }

    int h = (n0 + wc * 64) >> 6;   // head for this wave's 64 cols
    float asv[4], adv[4];
#pragma unroll
    for (int n = 0; n < 4; n++) {
        asv[n] = as1[h * HID + n * 16 + rl];
        adv[n] = ad1[h * HID + n * 16 + rl];
    }
#pragma unroll
    for (int m = 0; m < 4; m++) {
#pragma unroll
        for (int reg = 0; reg < 4; reg++) {
            int gr = m0 + wr * 64 + m * 16 + kg * 4 + reg;
            float pa = 0.f, pd = 0.f;
#pragma unroll
            for (int n = 0; n < 4; n++) {
                float v = acc[m][n][reg];
                pa += v * asv[n];
                pd += v * adv[n];
            }
#pragma unroll
            for (int o = 8; o; o >>= 1) { pa += __shfl_xor(pa, o); pd += __shfl_xor(pd, o); }
            if (gr < N_NODES) {
#pragma unroll
                for (int n = 0; n < 4; n++) {
                    int gc = n0 + wc * 64 + n * 16 + rl;
                    h1b[(size_t)gr * HO + gc] = f2bfu(acc[m][n][reg]);
                }
                if (rl == 0) {
                    es1[gr * HEADS + h] = pa;
                    ed1[gr * HEADS + h] = pd;
                }
            }
        }
    }
}

// --------------- CSR build ---------------
__global__ __launch_bounds__(256) void hist_kernel(const int* __restrict__ ei, int* __restrict__ deg) {
    int e = blockIdx.x * blockDim.x + threadIdx.x;
    if (e >= E2) return;
    int dst = (e < N_EDGES) ? ei[N_EDGES + e] : (e - N_EDGES);
    atomicAdd(&deg[dst], 1);
}

#define NBLK_SCAN ((N_NODES + 255) / 256)   // 196
__global__ __launch_bounds__(256) void scan1_kernel(const int* __restrict__ deg, int* __restrict__ bsum) {
    int i = blockIdx.x * 256 + threadIdx.x;
    int v = (i < N_NODES) ? deg[i] : 0;
#pragma unroll
    for (int o = 32; o; o >>= 1) v += __shfl_xor(v, o);
    __shared__ int ws_[4];
    if ((threadIdx.x & 63) == 0) ws_[threadIdx.x >> 6] = v;
    __syncthreads();
    if (threadIdx.x == 0) bsum[blockIdx.x] = ws_[0] + ws_[1] + ws_[2] + ws_[3];
}

__global__ __launch_bounds__(256) void scan2_kernel(const int* __restrict__ bsum, int* __restrict__ bbase) {
    int t = threadIdx.x;
    int v = (t < NBLK_SCAN) ? bsum[t] : 0;
    __shared__ int s[256];
    s[t] = v; __syncthreads();
    for (int o = 1; o < 256; o <<= 1) {
        int tv = (t >= o) ? s[t - o] : 0;
        __syncthreads();
        s[t] += tv;
        __syncthreads();
    }
    if (t < NBLK_SCAN) bbase[t] = s[t] - v;   // exclusive
}

__global__ __launch_bounds__(256) void scan3_kernel(const int* __restrict__ deg,
                                                    const int* __restrict__ bbase,
                                                    int* __restrict__ off) {
    int t = threadIdx.x;
    int i = blockIdx.x * 256 + t;
    int v = (i < N_NODES) ? deg[i] : 0;
    int lane = t & 63, wid = t >> 6;
    int sc = v;
#pragma unroll
    for (int o = 1; o < 64; o <<= 1) {
        int tv = __shfl_up(sc, o);
        if (lane >= o) sc += tv;
    }
    __shared__ int wsum[4];
    if (lane == 63) wsum[wid] = sc;
    __syncthreads();
    int wbase = 0;
    for (int k = 0; k < 4; k++) if (k < wid) wbase += wsum[k];
    if (i < N_NODES) off[i] = bbase[blockIdx.x] + wbase + sc - v;
}

__global__ __launch_bounds__(256) void fill_kernel(const int* __restrict__ ei,
                                                   const int* __restrict__ off,
                                                   int* __restrict__ cursor,
                                                   int* __restrict__ srcs) {
    int e = blockIdx.x * blockDim.x + threadIdx.x;
    if (e >= E2) return;
    int src, dst;
    if (e < N_EDGES) { src = ei[e]; dst = ei[N_EDGES + e]; }
    else { src = dst = e - N_EDGES; }
    int pos = atomicAdd(&cursor[dst], 1);
    srcs[off[dst] + pos] = src;
}

// --------------- layer-1 fused: score + softmax (no-max) + aggregation + bias + ELU
// --------------- + layer-2 GEMM (512->16) + attention scalars, all in one pass ---------------
// one wave per dst node; lane covers feats [8*lane, 8*lane+8), head = lane>>3.
// Epilogue: row staged to LDS, lane=(q,cls) dots 128 feats with LDS-transposed bf16 W2.
__global__ __launch_bounds__(256) void agg1_kernel(const uint4* __restrict__ h1v,
                                                   const float* __restrict__ es1,
                                                   const float* __restrict__ ed1,
                                                   const int* __restrict__ srcs,
                                                   const int* __restrict__ off,
                                                   const int* __restrict__ deg,
                                                   const float* __restrict__ b1,
                                                   const float* __restrict__ W2,
                                                   const float* __restrict__ as2,
                                                   const float* __restrict__ ad2,
                                                   unsigned short* __restrict__ h2b,
                                                   float* __restrict__ es2,
                                                   float* __restrict__ ed2) {
    __shared__ unsigned w2t[16 * 257];       // [cls][k] = bf16 pair (W2[2k][cls], W2[2k+1][cls]); 257-pad = conflict-free
    __shared__ unsigned rowbuf[4][256];      // per-wave post-ELU row, bf16 pairs
    int t = threadIdx.x;
    for (int i = t; i < 16 * 256; i += 256) {
        int cls = i >> 8, k = i & 255;
        w2t[cls * 257 + k] = packbf(W2[(2 * k) * N_CLS + cls], W2[(2 * k + 1) * N_CLS + cls]);
    }
    __syncthreads();

    int wid = t >> 6, lane = t & 63;
    int w = blockIdx.x * 4 + wid;            // grid = exactly 12500 blocks
    int h = lane >> 3;
    int o = off[w], d = deg[w];
    float edv = ed1[w * HEADS + h];
    float den = 0.f;
    float acc[8] = {};
    int s = srcs[o];
    uint4 raw = h1v[(size_t)s * (HO / 8) + lane];
    float esv = es1[s * HEADS + h];
    for (int i = 0; i < d; i++) {
        uint4 raw_n;
        float esv_n;
        if (i + 1 < d) {
            int s2 = srcs[o + i + 1];
            raw_n = h1v[(size_t)s2 * (HO / 8) + lane];
            esv_n = es1[s2 * HEADS + h];
        } else {
            raw_n = raw; esv_n = esv;
        }
        float e = esv + edv;
        e = (e > 0.f) ? e : NEG_SLOPE * e;
        float p = __expf(e);
        den += p;
        acc[0] += p * bf2f(raw.x << 16);
        acc[1] += p * bf2f(raw.x & 0xffff0000u);
        acc[2] += p * bf2f(raw.y << 16);
        acc[3] += p * bf2f(raw.y & 0xffff0000u);
        acc[4] += p * bf2f(raw.z << 16);
        acc[5] += p * bf2f(raw.z & 0xffff0000u);
        acc[6] += p * bf2f(raw.w << 16);
        acc[7] += p * bf2f(raw.w & 0xffff0000u);
        raw = raw_n; esv = esv_n;
    }
    float inv = 1.f / (den + 1e-16f);
    float r[8];
#pragma unroll
    for (int k = 0; k < 8; k++) {
        float v = acc[k] * inv + b1[lane * 8 + k];
        r[k] = (v > 0.f) ? v : (__expf(v) - 1.f);
    }
#pragma unroll
    for (int k = 0; k < 4; k++)
        rowbuf[wid][lane * 4 + k] = packbf(r[2 * k], r[2 * k + 1]);
    __syncthreads();

    // layer-2: lane (q=lane>>4, cls=lane&15) dots feats [q*128, q*128+128)
    int cls = lane & 15, q = lane >> 4;
    const unsigned* wrow = &w2t[cls * 257 + q * 64];
    const unsigned* rrow = &rowbuf[wid][q * 64];
    float hacc = 0.f;
#pragma unroll 8
    for (int kk = 0; kk < 64; kk++) {
        unsigned rv = rrow[kk], wv = wrow[kk];
        hacc += bf2f(rv << 16) * bf2f(wv << 16) + bf2f(rv & 0xffff0000u) * bf2f(wv & 0xffff0000u);
    }
    hacc += __shfl_xor(hacc, 16);
    hacc += __shfl_xor(hacc, 32);            // every lane now has h2[cls]
    float sa = hacc * as2[cls], sd = hacc * ad2[cls];
#pragma unroll
    for (int o2 = 8; o2; o2 >>= 1) { sa += __shfl_xor(sa, o2); sd += __shfl_xor(sd, o2); }
    if (lane < N_CLS) h2b[(size_t)w * N_CLS + cls] = f2bfu(hacc);
    if (lane == 0) { es2[w] = sa; ed2[w] = sd; }
}

// --------------- layer-2 fused score + softmax (no-max) + aggregation + log_softmax ---------------
__global__ __launch_bounds__(256) void agg2_kernel(const unsigned short* __restrict__ h2b,
                                                   const float* __restrict__ es2,
                                                   const float* __restrict__ ed2,
                                                   const int* __restrict__ srcs,
                                                   const int* __restrict__ off,
                                                   const int* __restrict__ deg,
                                                   const float* __restrict__ b2,
                                                   float* __restrict__ out) {
    int w = (blockIdx.x * blockDim.x + threadIdx.x) >> 6;
    int lane = threadIdx.x & 63;
    if (w >= N_NODES) return;
    int c = lane & 15, j = lane >> 4;
    int o = off[w], d = deg[w];
    float edv = ed2[w];
    float den = 0.f, acc = 0.f;
    for (int i = j; i < d; i += 4) {
        int s = srcs[o + i];
        float e = es2[s] + edv;
        e = (e > 0.f) ? e : NEG_SLOPE * e;
        float p = __expf(e);
        den += p;
        acc += p * bf2f((unsigned)h2b[s * N_CLS + c] << 16);
    }
#pragma unroll
    for (int o2 = 16; o2 <= 32; o2 <<= 1) {
        den += __shfl_xor(den, o2);
        acc += __shfl_xor(acc, o2);
    }
    float v = acc / (den + 1e-16f) + b2[c];
    float mm = v;
#pragma unroll
    for (int o2 = 8; o2; o2 >>= 1) mm = fmaxf(mm, __shfl_xor(mm, o2));
    float se = __expf(v - mm);
#pragma unroll
    for (int o2 = 8; o2; o2 >>= 1) se += __shfl_xor(se, o2);
    if (lane < N_CLS) out[w * N_CLS + c] = v - mm - logf(se);
}

extern "C" void kernel_launch(void* const* d_in, const int* in_sizes, int n_in,
                              void* d_out, int out_size, void* d_ws, size_t ws_size,
                              hipStream_t stream) {
    const float* x   = (const float*)d_in[0];
    const int*   ei  = (const int*)d_in[1];
    const float* W1  = (const float*)d_in[2];
    const float* as1 = (const float*)d_in[3];
    const float* ad1 = (const float*)d_in[4];
    const float* b1  = (const float*)d_in[5];
    const float* W2  = (const float*)d_in[6];
    const float* as2 = (const float*)d_in[7];
    const float* ad2 = (const float*)d_in[8];
    const float* b2  = (const float*)d_in[9];
    float* out = (float*)d_out;

    // workspace carve
    unsigned short* usw = (unsigned short*)d_ws;
    unsigned short* h1b  = usw;                                   // 25.6M (row-major)
    unsigned short* wt   = h1b + (size_t)N_NODES * HO;            // 131k
    unsigned short* h2b  = wt + F_IN * HO;                        // 800k
    float* fw = (float*)(h2b + (size_t)N_NODES * N_CLS);
    float* es1  = fw;                                             // 400k
    float* ed1  = es1 + (size_t)N_NODES * HEADS;                  // 400k
    float* es2  = ed1 + (size_t)N_NODES * HEADS;                  // 50k
    float* ed2  = es2 + N_NODES;                                  // 50k
    int* deg    = (int*)(ed2 + N_NODES);                          // 50k  <- memset
    int* cursor = deg + N_NODES;                                  // 50k  <- memset
    int* off    = cursor + N_NODES;                               // 50k
    int* srcs   = off + N_NODES;                                  // E2 + pad
    int* bsum   = srcs + E2 + 16;                                 // 256
    int* bbase  = bsum + 256;                                     // 256

    hipMemsetAsync(deg, 0, 2 * N_NODES * sizeof(int), stream);  // deg + cursor

    // W1 transpose+convert
    convert_wt_kernel<<<(F_IN * HO + 255) / 256, 256, 0, stream>>>(W1, wt);

    // layer 1 GEMM (bf16 MFMA, fp32-A in-register convert, fused attention scalars)
    gemm1_mfma_kernel<<<dim3(HO / 128, (N_NODES + 127) / 128), 256, 0, stream>>>(
        x, wt, as1, ad1, h1b, es1, ed1);

    // CSR build
    hist_kernel<<<(E2 + 255) / 256, 256, 0, stream>>>(ei, deg);
    scan1_kernel<<<NBLK_SCAN, 256, 0, stream>>>(deg, bsum);
    scan2_kernel<<<1, 256, 0, stream>>>(bsum, bbase);
    scan3_kernel<<<NBLK_SCAN, 256, 0, stream>>>(deg, bbase, off);
    fill_kernel<<<(E2 + 255) / 256, 256, 0, stream>>>(ei, off, cursor, srcs);

    // layer-1 aggregation + fused layer-2 GEMM/attn scalars; one wave per node
    agg1_kernel<<<N_NODES / 4, 256, 0, stream>>>((const uint4*)h1b, es1, ed1, srcs, off, deg,
                                                 b1, W2, as2, ad2, h2b, es2, ed2);

    // layer-2 aggregation + log_softmax
    agg2_kernel<<<(N_NODES + 3) / 4, 256, 0, stream>>>(h2b, es2, ed2, srcs, off, deg, b2, out);
}